// Round 2
// baseline (1247.287 us; speedup 1.0000x reference)
//
#include <hip/hip_runtime.h>
#include <hip/hip_bf16.h>
#include <stdint.h>

// MLA forward, bf16 MFMA pipeline.
// Shapes: B=1 S=2048 HID=2048 H=16 QLR=1536 KVLR=512 NOPE=128 ROPE=64 VD=128 QKD=192.

using bf16 = __hip_bfloat16;
typedef __bf16 bf16x8 __attribute__((ext_vector_type(8)));
typedef float f32x4 __attribute__((ext_vector_type(4)));

#define S_LEN 2048
#define NHEAD 16

static __device__ __forceinline__ void gload16(const void* g, void* l) {
  __builtin_amdgcn_global_load_lds(
      (const __attribute__((address_space(1))) unsigned int*)g,
      (__attribute__((address_space(3))) unsigned int*)l, 16, 0, 0);
}

// ---------------- fp32 -> bf16 convert with optional row padding (zeros) ----
__global__ void cvt_pad(const float* __restrict__ src, bf16* __restrict__ dst,
                        int rows, int cols, int rowspad) {
  size_t total = (size_t)rowspad * cols;
  for (size_t i = (size_t)blockIdx.x * blockDim.x + threadIdx.x; i < total;
       i += (size_t)gridDim.x * blockDim.x) {
    int r = (int)(i / cols);
    int c = (int)(i % cols);
    float v = (r < rows) ? src[(size_t)r * cols + c] : 0.0f;
    dst[i] = __float2bfloat16(v);
  }
}

// ---------------- wkv_bT[h][c][d] = wkv_b[h*256+d][c], d<128 ----------------
__global__ void mk_wkvbT(const bf16* __restrict__ wkvb, bf16* __restrict__ wt) {
  size_t total = 16ull * 512 * 128;
  for (size_t i = (size_t)blockIdx.x * blockDim.x + threadIdx.x; i < total;
       i += (size_t)gridDim.x * blockDim.x) {
    int h = (int)(i >> 16);          // 512*128
    int c = (int)((i >> 7) & 511);
    int d = (int)(i & 127);
    wt[i] = wkvb[((size_t)(h * 256 + d)) * 512 + c];
  }
}

// ---------------- row RMSNorm (bf16 in -> bf16 out) -------------------------
__global__ void rmsnorm_bf16(const bf16* __restrict__ in, const float* __restrict__ w,
                             bf16* __restrict__ out, int cols) {
  const int r = blockIdx.x, tid = threadIdx.x;
  const bf16* row = in + (size_t)r * cols;
  float ss = 0.f;
  for (int c = tid; c < cols; c += 256) {
    float v = __bfloat162float(row[c]);
    ss += v * v;
  }
  for (int m = 32; m >= 1; m >>= 1) ss += __shfl_xor(ss, m, 64);
  __shared__ float red[4];
  if ((tid & 63) == 0) red[tid >> 6] = ss;
  __syncthreads();
  ss = red[0] + red[1] + red[2] + red[3];
  float inv = rsqrtf(ss / (float)cols + 1e-6f);
  for (int c = tid; c < cols; c += 256)
    out[(size_t)r * cols + c] = __float2bfloat16(__bfloat162float(row[c]) * inv * w[c]);
}

// ---------------- kv post: rmsnorm(kv) + rope(k_pe) -> keff [t][576] --------
__global__ void kv_post(const float* __restrict__ kvf, const float* __restrict__ kvw,
                        bf16* __restrict__ keff) {
  const int t = blockIdx.x, tid = threadIdx.x;
  const float* row = kvf + (size_t)t * 640;
  float ss = 0.f;
  for (int c = tid; c < 512; c += 256) { float v = row[c]; ss += v * v; }
  for (int m = 32; m >= 1; m >>= 1) ss += __shfl_xor(ss, m, 64);
  __shared__ float red[4];
  if ((tid & 63) == 0) red[tid >> 6] = ss;
  __syncthreads();
  ss = red[0] + red[1] + red[2] + red[3];
  float inv = rsqrtf(ss * (1.0f / 512.0f) + 1e-6f);
  for (int c = tid; c < 512; c += 256)
    keff[(size_t)t * 576 + c] = __float2bfloat16(row[c] * inv * kvw[c]);
  if (tid < 64) {
    int j = tid, fr = j & 31;
    float freq = expf(-(float)fr * (1.0f / 32.0f) * 9.210340371976184f); // ln(10000)
    float ang = (float)t * freq;
    float cs = cosf(ang), sn = sinf(ang);
    float x1 = row[512 + j];
    float x2 = row[512 + (j < 32 ? j + 32 : j - 32)];
    float v = x1 * cs + (j < 32 ? -x2 : x2) * sn;
    keff[(size_t)t * 576 + 512 + j] = __float2bfloat16(v);
  }
}

// ---------------- q post: rope(q_pe) -> Qeff[h][s][512..576] ----------------
__global__ void q_post(const bf16* __restrict__ q, bf16* __restrict__ Qeff) {
  const int s = blockIdx.x, tid = threadIdx.x;
  for (int idx = tid; idx < 1024; idx += 256) {
    int h = idx >> 6, j = idx & 63, fr = j & 31;
    float freq = expf(-(float)fr * (1.0f / 32.0f) * 9.210340371976184f);
    float ang = (float)s * freq;
    float cs = cosf(ang), sn = sinf(ang);
    float x1 = __bfloat162float(q[(size_t)s * 3072 + h * 192 + 128 + j]);
    float x2 = __bfloat162float(q[(size_t)s * 3072 + h * 192 + 128 + (j < 32 ? j + 32 : j - 32)]);
    float v = x1 * cs + (j < 32 ? -x2 : x2) * sn;
    Qeff[((size_t)h * S_LEN + s) * 576 + 512 + j] = __float2bfloat16(v);
  }
}

// ---------------- kvT[c][t] = keff[t][c], c<512 (32x32 LDS transpose) -------
__global__ void transpose_k(const bf16* __restrict__ keff, bf16* __restrict__ kvT) {
  __shared__ bf16 tle[32][33];
  const int bx = blockIdx.x * 32;  // c
  const int by = blockIdx.y * 32;  // t
  const int x = threadIdx.x & 31, y = threadIdx.x >> 5; // 32x8
  for (int yy = y; yy < 32; yy += 8)
    tle[yy][x] = keff[(size_t)(by + yy) * 576 + bx + x];
  __syncthreads();
  for (int yy = y; yy < 32; yy += 8)
    kvT[(size_t)(bx + yy) * 2048 + by + x] = tle[x][yy];
}

// ---------------- GEMM: C[m][n] = sum_k A[m][k]*B[n][k] (+bias[n]) ----------
// 128x128 tile, BK=64, 4 waves, mfma 16x16x32 bf16, global_load_lds staging.
template <bool BIAS, bool BF16OUT>
__global__ __launch_bounds__(256)
void gemm_bt(const bf16* __restrict__ A, const bf16* __restrict__ B,
             const float* __restrict__ bias, void* __restrict__ Cv,
             int lda, int ldb, int ldc, int K, int Nreal,
             long long bA, long long bB, long long bC) {
  __shared__ bf16 As[8192];
  __shared__ bf16 Bs[8192];
  const int tid = threadIdx.x;
  const int wave = tid >> 6, lane = tid & 63;
  const int lo = lane & 15, hi = lane >> 4;
  const int wr = wave >> 1, wc = wave & 1;
  const size_t m0 = (size_t)blockIdx.y * 128, n0 = (size_t)blockIdx.x * 128;
  A += (size_t)blockIdx.z * (size_t)bA;
  B += (size_t)blockIdx.z * (size_t)bB;
  const int srow = lane >> 3;        // 0..7
  const int scol = (lane & 7) * 8;   // 0..56
  f32x4 acc[4][4] = {};
  for (int k0 = 0; k0 < K; k0 += 64) {
    __syncthreads();
#pragma unroll
    for (int i = 0; i < 4; ++i) {
      const int blk = wave * 4 + i;        // 0..15 (1KB chunks)
      const int row = blk * 8 + srow;      // 0..127
      gload16(A + (m0 + row) * (size_t)lda + k0 + scol, As + blk * 512);
      gload16(B + (n0 + row) * (size_t)ldb + k0 + scol, Bs + blk * 512);
    }
    __syncthreads();
#pragma unroll
    for (int kk = 0; kk < 2; ++kk) {
      bf16x8 af[4], bfr[4];
#pragma unroll
      for (int m = 0; m < 4; ++m)
        af[m] = *(const bf16x8*)&As[(wr * 64 + m * 16 + lo) * 64 + kk * 32 + hi * 8];
#pragma unroll
      for (int n = 0; n < 4; ++n)
        bfr[n] = *(const bf16x8*)&Bs[(wc * 64 + n * 16 + lo) * 64 + kk * 32 + hi * 8];
#pragma unroll
      for (int m = 0; m < 4; ++m)
#pragma unroll
        for (int n = 0; n < 4; ++n)
          acc[m][n] = __builtin_amdgcn_mfma_f32_16x16x32_bf16(af[m], bfr[n], acc[m][n], 0, 0, 0);
    }
  }
  float* Cf = (float*)Cv;
  bf16* Cb = (bf16*)Cv;
  const size_t cbase = (size_t)blockIdx.z * (size_t)bC;
#pragma unroll
  for (int m = 0; m < 4; ++m) {
    const size_t row = m0 + wr * 64 + m * 16 + hi * 4;
#pragma unroll
    for (int n = 0; n < 4; ++n) {
      const int col = (int)n0 + wc * 64 + n * 16 + lo;
      if (col < Nreal) {
        const float bv = BIAS ? bias[col] : 0.0f;
#pragma unroll
        for (int j = 0; j < 4; ++j) {
          const float v = acc[m][n][j] + bv;
          const size_t off = cbase + (row + j) * (size_t)ldc + col;
          if (BF16OUT) Cb[off] = __float2bfloat16(v);
          else         Cf[off] = v;
        }
      }
    }
  }
}

// ---------------- flash attention (MLA absorbed), swapped-QK^T --------------
// grid (32 qblocks desc, 16 heads), 4 waves; wave w owns q rows [qb*64+w*16,+16).
// LDS: rope region [64][64] at 0 (8KB) + nope region [64][512] at 4096 (64KB),
// both XOR-swizzled (chunk ^= row&7) via pre-swizzled global_load_lds source.
// S^T = mfma(K,Q): lane lo = q, per-lane online softmax; P rebuilt to PV
// A-fragment layout with 16 ds_bpermute. V from pre-transposed kvT (L2).
__global__ __launch_bounds__(256, 2)
void attn_fwd(const bf16* __restrict__ Qeff, const bf16* __restrict__ keff,
              const bf16* __restrict__ kvT, bf16* __restrict__ attnO) {
  const int qb = (int)(gridDim.x - 1 - blockIdx.x);
  const int h = blockIdx.y;
  const int tid = threadIdx.x, w = tid >> 6, lane = tid & 63;
  const int lo = lane & 15, hi = lane >> 4;
  const int x = lo & 7;
  const int e0 = hi ^ x, e1 = e0 ^ 4;
  __shared__ bf16 Klds[36864];  // 73728 B total
  const int q0 = qb * 64 + w * 16;

  bf16x8 Qf[18];
  {
    const bf16* qp = Qeff + ((size_t)h * S_LEN + q0 + lo) * 576 + hi * 8;
#pragma unroll
    for (int ks = 0; ks < 18; ++ks) Qf[ks] = *(const bf16x8*)(qp + ks * 32);
  }
  f32x4 o[32];
#pragma unroll
  for (int c = 0; c < 32; ++c) o[c] = (f32x4){0.f, 0.f, 0.f, 0.f};
  float mrow = -3e38f, lrow = 0.f;

  const bf16* vbase = kvT + (size_t)lo * 2048 + hi * 8;  // + c*32768 + t0 + tk*32

  const int ntile = qb + 1;
  for (int it = 0; it < ntile; ++it) {
    const int t0 = it * 64;
    __syncthreads();
    // ---- stage K tile: nope rows w*16..w*16+15 (1KB per row), rope 2 calls
    {
      const bf16* src = keff + (size_t)t0 * 576;
#pragma unroll
      for (int i = 0; i < 16; ++i) {
        const int r = w * 16 + i;
        gload16(src + (size_t)r * 576 + ((lane ^ (r & 7)) * 8),
                &Klds[4096 + r * 512]);
      }
#pragma unroll
      for (int i = 0; i < 2; ++i) {
        const int call = w * 2 + i;
        const int row = call * 8 + (lane >> 3);
        const int pc = lane & 7;
        gload16(src + (size_t)row * 576 + 512 + ((pc ^ (row & 7)) * 8),
                &Klds[call * 512]);
      }
    }
    __syncthreads();

    // ---- S^T = K · Q  (lane: lo = q, rows hi*4+j = t within fragment f)
    f32x4 sc[4];
#pragma unroll
    for (int f = 0; f < 4; ++f) sc[f] = (f32x4){0.f, 0.f, 0.f, 0.f};
#pragma unroll
    for (int ks = 0; ks < 18; ++ks) {
#pragma unroll
      for (int f = 0; f < 4; ++f) {
        const int row = f * 16 + lo;
        const bf16* kp = (ks < 16)
            ? &Klds[4096 + row * 512 + (ks >> 1) * 64 + ((ks & 1) ? e1 : e0) * 8]
            : &Klds[row * 64 + ((ks == 17) ? e1 : e0) * 8];
        bf16x8 kf = *(const bf16x8*)kp;
        sc[f] = __builtin_amdgcn_mfma_f32_16x16x32_bf16(kf, Qf[ks], sc[f], 0, 0, 0);
      }
    }

    // ---- masked scale + row max (row = q = lo; 16 vals/lane + 2 shuffles)
    const bool diag = (it == ntile - 1);
    const int q = q0 + lo;
    float rmax = -3e38f;
#pragma unroll
    for (int f = 0; f < 4; ++f)
#pragma unroll
      for (int j = 0; j < 4; ++j) {
        float v = sc[f][j] * 0.0721687836487032f; // 1/sqrt(192)
        if (diag && (t0 + f * 16 + hi * 4 + j > q)) v = -3e38f;
        sc[f][j] = v;
        rmax = fmaxf(rmax, v);
      }
    rmax = fmaxf(rmax, __shfl_xor(rmax, 16, 64));
    rmax = fmaxf(rmax, __shfl_xor(rmax, 32, 64));

    // ---- online softmax with deferred-max (skip rescale if growth <= 8)
    if (!__all(rmax <= mrow + 8.0f)) {
      const float mn = fmaxf(mrow, rmax);
      const float fsc = __expf(mrow - mn);
      mrow = mn;
      lrow *= fsc;
      float fscO[4];
#pragma unroll
      for (int j = 0; j < 4; ++j) fscO[j] = __shfl(fsc, hi * 4 + j, 64);
#pragma unroll
      for (int c = 0; c < 32; ++c)
#pragma unroll
        for (int j = 0; j < 4; ++j) o[c][j] *= fscO[j];
    }
    float rsum = 0.f;
    uint32_t d[4][2];
#pragma unroll
    for (int f = 0; f < 4; ++f) {
      float p[4];
#pragma unroll
      for (int j = 0; j < 4; ++j) {
        p[j] = __expf(sc[f][j] - mrow);
        rsum += p[j];
      }
#pragma unroll
      for (int i2 = 0; i2 < 2; ++i2) {
        uint32_t lo16 = (uint32_t)__bfloat16_as_ushort(__float2bfloat16(p[i2 * 2]));
        uint32_t hi16 = (uint32_t)__bfloat16_as_ushort(__float2bfloat16(p[i2 * 2 + 1]));
        d[f][i2] = lo16 | (hi16 << 16);
      }
    }
    rsum += __shfl_xor(rsum, 16, 64);
    rsum += __shfl_xor(rsum, 32, 64);
    lrow += rsum;

    // ---- PV: rebuild P into A-fragment layout (ds_bpermute), V from kvT
#pragma unroll
    for (int tk = 0; tk < 2; ++tk) {
      union { uint32_t u[4]; bf16x8 v; } pa;
#pragma unroll
      for (int dwi = 0; dwi < 4; ++dwi) {
        const int srcl = lo + ((2 * (hi & 1) + (dwi >> 1)) << 4);
        const uint32_t vA = (uint32_t)__shfl((int)d[2 * tk][dwi & 1], srcl, 64);
        const uint32_t vB = (uint32_t)__shfl((int)d[2 * tk + 1][dwi & 1], srcl, 64);
        pa.u[dwi] = (hi < 2) ? vA : vB;
      }
      const bf16* vb = vbase + t0 + tk * 32;
#pragma unroll
      for (int c = 0; c < 32; ++c) {
        bf16x8 vf = *(const bf16x8*)(vb + (size_t)c * 32768);
        o[c] = __builtin_amdgcn_mfma_f32_16x16x32_bf16(pa.v, vf, o[c], 0, 0, 0);
      }
    }
  }

  // ---- epilogue: rows q = q0 + hi*4+j, cols c = c*16+lo
  bf16* ob = attnO + ((size_t)h * S_LEN + q0) * 512;
#pragma unroll
  for (int j = 0; j < 4; ++j) {
    const float linv = 1.0f / __shfl(lrow, hi * 4 + j, 64);
#pragma unroll
    for (int c = 0; c < 32; ++c)
      ob[(size_t)(hi * 4 + j) * 512 + c * 16 + lo] = __float2bfloat16(o[c][j] * linv);
  }
}

// ---------------------------------------------------------------------------
extern "C" void kernel_launch(void* const* d_in, const int* in_sizes, int n_in,
                              void* d_out, int out_size, void* d_ws, size_t ws_size,
                              hipStream_t stream) {
  const float* x       = (const float*)d_in[0];
  const float* wq_a_w  = (const float*)d_in[1];
  const float* wq_a_b  = (const float*)d_in[2];
  const float* q_norm  = (const float*)d_in[3];
  const float* wq_b_w  = (const float*)d_in[4];
  const float* wq_b_b  = (const float*)d_in[5];
  const float* wkv_a_w = (const float*)d_in[6];
  const float* wkv_a_b = (const float*)d_in[7];
  const float* kv_norm = (const float*)d_in[8];
  const float* wkv_b_w = (const float*)d_in[9];
  const float* wo_w    = (const float*)d_in[10];
  const float* wo_bias = (const float*)d_in[11];
  float* out = (float*)d_out;

  char* p = (char*)d_ws;
  auto alloc = [&](size_t bytes) {
    char* r = p;
    p += (bytes + 255) & ~(size_t)255;
    return r;
  };
  bf16*  xb    = (bf16*)alloc(2048ull * 2048 * 2);
  bf16*  wqa   = (bf16*)alloc(1536ull * 2048 * 2);
  bf16*  wqb   = (bf16*)alloc(3072ull * 1536 * 2);
  bf16*  wkva  = (bf16*)alloc(640ull * 2048 * 2);   // padded 576->640
  bf16*  wkvb  = (bf16*)alloc(4096ull * 512 * 2);
  bf16*  wob   = (bf16*)alloc(2048ull * 2048 * 2);
  bf16*  wkvbT = (bf16*)alloc(16ull * 512 * 128 * 2);
  bf16*  qa    = (bf16*)alloc(2048ull * 1536 * 2);
  bf16*  qn    = (bf16*)alloc(2048ull * 1536 * 2);
  bf16*  qv    = (bf16*)alloc(2048ull * 3072 * 2);
  float* kvf   = (float*)alloc(2048ull * 640 * 4);
  bf16*  keff  = (bf16*)alloc(2048ull * 576 * 2);
  bf16*  kvT   = (bf16*)alloc(512ull * 2048 * 2);
  bf16*  Qeff  = (bf16*)alloc(16ull * 2048 * 576 * 2);
  bf16*  attnb = (bf16*)alloc(16ull * 2048 * 512 * 2);
  bf16*  oabs  = (bf16*)alloc(2048ull * 2048 * 2);

  // weight / input converts (fp32 -> bf16, pad wkv_a rows to 640 with zeros)
  cvt_pad<<<dim3(2048), 256, 0, stream>>>(x, xb, 2048, 2048, 2048);
  cvt_pad<<<dim3(2048), 256, 0, stream>>>(wq_a_w, wqa, 1536, 2048, 1536);
  cvt_pad<<<dim3(2048), 256, 0, stream>>>(wq_b_w, wqb, 3072, 1536, 3072);
  cvt_pad<<<dim3(1024), 256, 0, stream>>>(wkv_a_w, wkva, 576, 2048, 640);
  cvt_pad<<<dim3(1024), 256, 0, stream>>>(wkv_b_w, wkvb, 4096, 512, 4096);
  cvt_pad<<<dim3(2048), 256, 0, stream>>>(wo_w, wob, 2048, 2048, 2048);
  mk_wkvbT<<<dim3(1024), 256, 0, stream>>>(wkvb, wkvbT);

  // q_a = rmsnorm(x @ wq_a^T + b)
  gemm_bt<true, true><<<dim3(12, 16, 1), 256, 0, stream>>>(
      xb, wqa, wq_a_b, qa, 2048, 2048, 1536, 2048, 1536, 0, 0, 0);
  rmsnorm_bf16<<<2048, 256, 0, stream>>>(qa, q_norm, qn, 1536);
  // q = qn @ wq_b^T + b  -> [2048][3072] (bf16)
  gemm_bt<true, true><<<dim3(24, 16, 1), 256, 0, stream>>>(
      qn, wqb, wq_b_b, qv, 1536, 1536, 3072, 1536, 3072, 0, 0, 0);
  // kv_full = x @ wkv_a^T + b -> fp32 [2048][640] (576 valid)
  gemm_bt<true, false><<<dim3(5, 16, 1), 256, 0, stream>>>(
      xb, wkva, wkv_a_b, kvf, 2048, 2048, 640, 2048, 576, 0, 0, 0);
  kv_post<<<2048, 256, 0, stream>>>(kvf, kv_norm, keff);
  transpose_k<<<dim3(16, 64), 256, 0, stream>>>(keff, kvT);
  q_post<<<2048, 256, 0, stream>>>(qv, Qeff);
  // absorbed q_nope: Qeff[h][s][0..512] = q_nope[s][h] @ wkv_bT[h]
  gemm_bt<false, true><<<dim3(4, 16, 16), 256, 0, stream>>>(
      qv, wkvbT, nullptr, Qeff, 3072, 128, 576, 128, 512,
      192ll, 65536ll, 2048ll * 576);
  // attention
  attn_fwd<<<dim3(32, 16), 256, 0, stream>>>(Qeff, keff, kvT, attnb);
  // output absorb: oabs[s][h*128+d] = attn[h][s] @ wkv_b[h][128+d][:]
  gemm_bt<false, true><<<dim3(1, 16, 16), 256, 0, stream>>>(
      attnb, wkvb + 128ull * 512, nullptr, oabs, 512, 512, 2048, 512, 128,
      2048ll * 512, 256ll * 512, 128ll);
  // final: out = oabs @ wo^T + b (fp32 out)
  gemm_bt<true, false><<<dim3(16, 16, 1), 256, 0, stream>>>(
      oabs, wob, wo_bias, out, 2048, 2048, 2048, 2048, 2048, 0, 0, 0);
}

// Round 3
// 739.411 us; speedup vs baseline: 1.6869x; 1.6869x over previous
//
#include <hip/hip_runtime.h>
#include <hip/hip_bf16.h>
#include <stdint.h>

// MLA forward, bf16 MFMA pipeline.
// Shapes: B=1 S=2048 HID=2048 H=16 QLR=1536 KVLR=512 NOPE=128 ROPE=64 VD=128 QKD=192.

using bf16 = __hip_bfloat16;
typedef __bf16 bf16x8 __attribute__((ext_vector_type(8)));
typedef __bf16 bf16x4 __attribute__((ext_vector_type(4)));
typedef float f32x4 __attribute__((ext_vector_type(4)));

#define S_LEN 2048
#define NHEAD 16

static __device__ __forceinline__ void gload16(const void* g, void* l) {
  __builtin_amdgcn_global_load_lds(
      (const __attribute__((address_space(1))) unsigned int*)g,
      (__attribute__((address_space(3))) unsigned int*)l, 16, 0, 0);
}

// ---------------- fp32 -> bf16 convert, 4-wide, optional row padding --------
__global__ void cvt_pad4(const float* __restrict__ src, bf16* __restrict__ dst,
                         int rows, int cols, int rowspad) {
  size_t total = ((size_t)rowspad * cols) >> 2;
  for (size_t i = (size_t)blockIdx.x * blockDim.x + threadIdx.x; i < total;
       i += (size_t)gridDim.x * blockDim.x) {
    size_t e = i << 2;
    int r = (int)(e / cols);
    int c = (int)(e % cols);
    float4 v;
    if (r < rows) v = *(const float4*)(src + (size_t)r * cols + c);
    else          v = make_float4(0.f, 0.f, 0.f, 0.f);
    bf16x4 o;
    o[0] = (__bf16)__float2bfloat16(v.x);
    o[1] = (__bf16)__float2bfloat16(v.y);
    o[2] = (__bf16)__float2bfloat16(v.z);
    o[3] = (__bf16)__float2bfloat16(v.w);
    *(bf16x4*)(dst + e) = o;
  }
}

// ---------------- wkv_bT[h][c][d] = wkv_b[h*256+d][c], d<128 ----------------
__global__ void mk_wkvbT(const bf16* __restrict__ wkvb, bf16* __restrict__ wt) {
  size_t total = 16ull * 512 * 128;
  for (size_t i = (size_t)blockIdx.x * blockDim.x + threadIdx.x; i < total;
       i += (size_t)gridDim.x * blockDim.x) {
    int h = (int)(i >> 16);          // 512*128
    int c = (int)((i >> 7) & 511);
    int d = (int)(i & 127);
    wt[i] = wkvb[((size_t)(h * 256 + d)) * 512 + c];
  }
}

// ---------------- row RMSNorm (bf16 in -> bf16 out) -------------------------
__global__ void rmsnorm_bf16(const bf16* __restrict__ in, const float* __restrict__ w,
                             bf16* __restrict__ out, int cols) {
  const int r = blockIdx.x, tid = threadIdx.x;
  const bf16* row = in + (size_t)r * cols;
  float ss = 0.f;
  for (int c = tid; c < cols; c += 256) {
    float v = __bfloat162float(row[c]);
    ss += v * v;
  }
  for (int m = 32; m >= 1; m >>= 1) ss += __shfl_xor(ss, m, 64);
  __shared__ float red[4];
  if ((tid & 63) == 0) red[tid >> 6] = ss;
  __syncthreads();
  ss = red[0] + red[1] + red[2] + red[3];
  float inv = rsqrtf(ss / (float)cols + 1e-6f);
  for (int c = tid; c < cols; c += 256)
    out[(size_t)r * cols + c] = __float2bfloat16(__bfloat162float(row[c]) * inv * w[c]);
}

// ---------------- kv post: rmsnorm(kv) + rope(k_pe) -> keff [t][576] --------
__global__ void kv_post(const float* __restrict__ kvf, const float* __restrict__ kvw,
                        bf16* __restrict__ keff) {
  const int t = blockIdx.x, tid = threadIdx.x;
  const float* row = kvf + (size_t)t * 640;
  float ss = 0.f;
  for (int c = tid; c < 512; c += 256) { float v = row[c]; ss += v * v; }
  for (int m = 32; m >= 1; m >>= 1) ss += __shfl_xor(ss, m, 64);
  __shared__ float red[4];
  if ((tid & 63) == 0) red[tid >> 6] = ss;
  __syncthreads();
  ss = red[0] + red[1] + red[2] + red[3];
  float inv = rsqrtf(ss * (1.0f / 512.0f) + 1e-6f);
  for (int c = tid; c < 512; c += 256)
    keff[(size_t)t * 576 + c] = __float2bfloat16(row[c] * inv * kvw[c]);
  if (tid < 64) {
    int j = tid, fr = j & 31;
    float freq = expf(-(float)fr * (1.0f / 32.0f) * 9.210340371976184f); // ln(10000)
    float ang = (float)t * freq;
    float cs = cosf(ang), sn = sinf(ang);
    float x1 = row[512 + j];
    float x2 = row[512 + (j < 32 ? j + 32 : j - 32)];
    float v = x1 * cs + (j < 32 ? -x2 : x2) * sn;
    keff[(size_t)t * 576 + 512 + j] = __float2bfloat16(v);
  }
}

// ---------------- q post: rope(q_pe) -> Qeff[h][s][512..576] ----------------
__global__ void q_post(const bf16* __restrict__ q, bf16* __restrict__ Qeff) {
  const int s = blockIdx.x, tid = threadIdx.x;
  for (int idx = tid; idx < 1024; idx += 256) {
    int h = idx >> 6, j = idx & 63, fr = j & 31;
    float freq = expf(-(float)fr * (1.0f / 32.0f) * 9.210340371976184f);
    float ang = (float)s * freq;
    float cs = cosf(ang), sn = sinf(ang);
    float x1 = __bfloat162float(q[(size_t)s * 3072 + h * 192 + 128 + j]);
    float x2 = __bfloat162float(q[(size_t)s * 3072 + h * 192 + 128 + (j < 32 ? j + 32 : j - 32)]);
    float v = x1 * cs + (j < 32 ? -x2 : x2) * sn;
    Qeff[((size_t)h * S_LEN + s) * 576 + 512 + j] = __float2bfloat16(v);
  }
}

// ---------------- kvT[c][t] = keff[t][c], c<512 (32x32 LDS transpose) -------
__global__ void transpose_k(const bf16* __restrict__ keff, bf16* __restrict__ kvT) {
  __shared__ bf16 tle[32][33];
  const int bx = blockIdx.x * 32;  // c
  const int by = blockIdx.y * 32;  // t
  const int x = threadIdx.x & 31, y = threadIdx.x >> 5; // 32x8
  for (int yy = y; yy < 32; yy += 8)
    tle[yy][x] = keff[(size_t)(by + yy) * 576 + bx + x];
  __syncthreads();
  for (int yy = y; yy < 32; yy += 8)
    kvT[(size_t)(bx + yy) * 2048 + by + x] = tle[x][yy];
}

// ---------------- GEMM: C[m][n] = sum_k A[m][k]*B[n][k] (+bias[n]) ----------
// 128x128 tile, BK=64, 4 waves, mfma 16x16x32 bf16, global_load_lds staging.
template <bool BIAS, bool BF16OUT>
__global__ __launch_bounds__(256)
void gemm_bt(const bf16* __restrict__ A, const bf16* __restrict__ B,
             const float* __restrict__ bias, void* __restrict__ Cv,
             int lda, int ldb, int ldc, int K, int Nreal,
             long long bA, long long bB, long long bC) {
  __shared__ bf16 As[8192];
  __shared__ bf16 Bs[8192];
  const int tid = threadIdx.x;
  const int wave = tid >> 6, lane = tid & 63;
  const int lo = lane & 15, hi = lane >> 4;
  const int wr = wave >> 1, wc = wave & 1;
  const size_t m0 = (size_t)blockIdx.y * 128, n0 = (size_t)blockIdx.x * 128;
  A += (size_t)blockIdx.z * (size_t)bA;
  B += (size_t)blockIdx.z * (size_t)bB;
  const int srow = lane >> 3;        // 0..7
  const int scol = (lane & 7) * 8;   // 0..56
  f32x4 acc[4][4] = {};
  for (int k0 = 0; k0 < K; k0 += 64) {
    __syncthreads();
#pragma unroll
    for (int i = 0; i < 4; ++i) {
      const int blk = wave * 4 + i;        // 0..15 (1KB chunks)
      const int row = blk * 8 + srow;      // 0..127
      gload16(A + (m0 + row) * (size_t)lda + k0 + scol, As + blk * 512);
      gload16(B + (n0 + row) * (size_t)ldb + k0 + scol, Bs + blk * 512);
    }
    __syncthreads();
#pragma unroll
    for (int kk = 0; kk < 2; ++kk) {
      bf16x8 af[4], bfr[4];
#pragma unroll
      for (int m = 0; m < 4; ++m)
        af[m] = *(const bf16x8*)&As[(wr * 64 + m * 16 + lo) * 64 + kk * 32 + hi * 8];
#pragma unroll
      for (int n = 0; n < 4; ++n)
        bfr[n] = *(const bf16x8*)&Bs[(wc * 64 + n * 16 + lo) * 64 + kk * 32 + hi * 8];
#pragma unroll
      for (int m = 0; m < 4; ++m)
#pragma unroll
        for (int n = 0; n < 4; ++n)
          acc[m][n] = __builtin_amdgcn_mfma_f32_16x16x32_bf16(af[m], bfr[n], acc[m][n], 0, 0, 0);
    }
  }
  float* Cf = (float*)Cv;
  bf16* Cb = (bf16*)Cv;
  const size_t cbase = (size_t)blockIdx.z * (size_t)bC;
#pragma unroll
  for (int m = 0; m < 4; ++m) {
    const size_t row = m0 + wr * 64 + m * 16 + hi * 4;
#pragma unroll
    for (int n = 0; n < 4; ++n) {
      const int col = (int)n0 + wc * 64 + n * 16 + lo;
      if (col < Nreal) {
        const float bv = BIAS ? bias[col] : 0.0f;
#pragma unroll
        for (int j = 0; j < 4; ++j) {
          const float v = acc[m][n][j] + bv;
          const size_t off = cbase + (row + j) * (size_t)ldc + col;
          if (BF16OUT) Cb[off] = __float2bfloat16(v);
          else         Cf[off] = v;
        }
      }
    }
  }
}

// ---------------- flash attention (MLA absorbed), c-split PV ----------------
// grid (32 qblocks desc, 16 heads), 4 waves, 1 block/CU.
// QK: wave w computes S^T for q rows w*16..+16 (swapped mfma(K,Q), in-lane
// softmax), writes P slice to shared Plds[64][72].
// PV: wave w computes ALL 64 q rows x its 128 of 512 output dims; V frags
// from pre-transposed kvT (global, L2-resident), each reused by 4 MFMAs.
// K tile double-buffered in LDS; next tile staged via global_load_lds right
// after the top barrier -> full-tile latency hiding. 2 barriers/tile.
__global__ __launch_bounds__(256, 1)
void attn_fwd(const bf16* __restrict__ Qeff, const bf16* __restrict__ keff,
              const bf16* __restrict__ kvT, bf16* __restrict__ attnO) {
  const int qb = (int)(gridDim.x - 1 - blockIdx.x);
  const int h = blockIdx.y;
  const int tid = threadIdx.x, w = tid >> 6, lane = tid & 63;
  const int lo = lane & 15, hi = lane >> 4;
  const int x7 = lo & 7;
  const int e0 = hi ^ x7, e1 = e0 ^ 4;
  __shared__ bf16 Klds[2][36864];   // [rope 64x64 | nope 64x512], swizzled
  __shared__ bf16 Plds[64][72];     // P[q][t], pad 72
  __shared__ float Flds[64];        // per-row rescale factor
  __shared__ float Llds[64];        // per-row final l
  const int q0 = qb * 64 + w * 16;  // this wave's QK q rows

  // Q fragments for rows q0..q0+15 (lane lo = row, hi*8 = k offset)
  bf16x8 Qf[18];
  {
    const bf16* qp = Qeff + ((size_t)h * S_LEN + q0 + lo) * 576 + hi * 8;
#pragma unroll
    for (int ks = 0; ks < 18; ++ks) Qf[ks] = *(const bf16x8*)(qp + ks * 32);
  }
  // acc[qg][cg]: q rows qg*16+hi*4+j, cols w*128+cg*16+lo
  f32x4 o[4][8];
#pragma unroll
  for (int qg = 0; qg < 4; ++qg)
#pragma unroll
    for (int cg = 0; cg < 8; ++cg) o[qg][cg] = (f32x4){0.f, 0.f, 0.f, 0.f};
  float mrow = -3e38f, lrow = 0.f;

  const bf16* vbase = kvT + (size_t)(w * 128 + lo) * 2048 + hi * 8;

  const int ntile = qb + 1;
  // prologue: stage tile 0 into buf 0
  {
    const bf16* src = keff;
#pragma unroll
    for (int i = 0; i < 16; ++i) {
      const int r = w * 16 + i;
      gload16(src + (size_t)r * 576 + ((lane ^ (r & 7)) * 8), &Klds[0][4096 + r * 512]);
    }
#pragma unroll
    for (int i = 0; i < 2; ++i) {
      const int call = w * 2 + i;
      const int row = call * 8 + (lane >> 3);
      gload16(src + (size_t)row * 576 + 512 + (((lane & 7) ^ (row & 7)) * 8),
              &Klds[0][call * 512]);
    }
  }

  for (int it = 0; it < ntile; ++it) {
    const int t0 = it * 64;
    const int b = it & 1;
    __syncthreads();  // drains vmcnt: K(it) ready; P(it-1)/F consumed by all

    // stage K(it+1) into the other buffer (in flight across this whole tile)
    if (it + 1 < ntile) {
      const bf16* src = keff + (size_t)(t0 + 64) * 576;
#pragma unroll
      for (int i = 0; i < 16; ++i) {
        const int r = w * 16 + i;
        gload16(src + (size_t)r * 576 + ((lane ^ (r & 7)) * 8), &Klds[b ^ 1][4096 + r * 512]);
      }
#pragma unroll
      for (int i = 0; i < 2; ++i) {
        const int call = w * 2 + i;
        const int row = call * 8 + (lane >> 3);
        gload16(src + (size_t)row * 576 + 512 + (((lane & 7) ^ (row & 7)) * 8),
                &Klds[b ^ 1][call * 512]);
      }
    }

    // V fragments for this tile (independent of P; latency hidden under QK)
    bf16x8 vf[2][8];
#pragma unroll
    for (int tk = 0; tk < 2; ++tk)
#pragma unroll
      for (int cg = 0; cg < 8; ++cg)
        vf[tk][cg] = *(const bf16x8*)(vbase + (size_t)cg * 32768 + t0 + tk * 32);

    // ---- S^T = K · Q  (lane: lo = q, rows hi*4+j+f*16 = t)
    f32x4 sc[4];
#pragma unroll
    for (int f = 0; f < 4; ++f) sc[f] = (f32x4){0.f, 0.f, 0.f, 0.f};
#pragma unroll
    for (int ks = 0; ks < 18; ++ks) {
#pragma unroll
      for (int f = 0; f < 4; ++f) {
        const int row = f * 16 + lo;
        const bf16* kp = (ks < 16)
            ? &Klds[b][4096 + row * 512 + (ks >> 1) * 64 + ((ks & 1) ? e1 : e0) * 8]
            : &Klds[b][row * 64 + ((ks == 17) ? e1 : e0) * 8];
        bf16x8 kf = *(const bf16x8*)kp;
        sc[f] = __builtin_amdgcn_mfma_f32_16x16x32_bf16(kf, Qf[ks], sc[f], 0, 0, 0);
      }
    }

    // ---- masked scale + row max (row q = q0 + lo)
    const bool diag = (it == ntile - 1);
    const int q = q0 + lo;
    float rmax = -3e38f;
#pragma unroll
    for (int f = 0; f < 4; ++f)
#pragma unroll
      for (int j = 0; j < 4; ++j) {
        float v = sc[f][j] * 0.0721687836487032f; // 1/sqrt(192)
        if (diag && (t0 + f * 16 + hi * 4 + j > q)) v = -3e38f;
        sc[f][j] = v;
        rmax = fmaxf(rmax, v);
      }
    rmax = fmaxf(rmax, __shfl_xor(rmax, 16, 64));
    rmax = fmaxf(rmax, __shfl_xor(rmax, 32, 64));

    // ---- online softmax (unconditional rescale; factor shared via Flds)
    const float mn = fmaxf(mrow, rmax);
    const float fsc = __expf(mrow - mn);
    mrow = mn;
    lrow *= fsc;
    if (hi == 0) Flds[w * 16 + lo] = fsc;
    float rsum = 0.f;
#pragma unroll
    for (int f = 0; f < 4; ++f) {
      float p[4];
#pragma unroll
      for (int j = 0; j < 4; ++j) {
        p[j] = __expf(sc[f][j] - mrow);
        rsum += p[j];
      }
#pragma unroll
      for (int i2 = 0; i2 < 2; ++i2) {
        uint32_t lo16 = (uint32_t)__bfloat16_as_ushort(__float2bfloat16(p[i2 * 2]));
        uint32_t hi16 = (uint32_t)__bfloat16_as_ushort(__float2bfloat16(p[i2 * 2 + 1]));
        // P[q][t] pairs along t: t = f*16 + hi*4 + 2*i2
        *(uint32_t*)&Plds[w * 16 + lo][f * 16 + hi * 4 + 2 * i2] = lo16 | (hi16 << 16);
      }
    }
    rsum += __shfl_xor(rsum, 16, 64);
    rsum += __shfl_xor(rsum, 32, 64);
    lrow += rsum;

    __syncthreads();  // P + F visible to all waves

    // ---- rescale o by per-row factor (broadcast reads)
    f32x4 ff[4];
#pragma unroll
    for (int qg = 0; qg < 4; ++qg) ff[qg] = *(const f32x4*)&Flds[qg * 16 + hi * 4];
#pragma unroll
    for (int qg = 0; qg < 4; ++qg)
#pragma unroll
      for (int cg = 0; cg < 8; ++cg)
#pragma unroll
        for (int j = 0; j < 4; ++j) o[qg][cg][j] *= ff[qg][j];

    // ---- PV: o[all 64 q][this wave's 128 c] += P · V
#pragma unroll
    for (int tk = 0; tk < 2; ++tk) {
      bf16x8 pa[4];
#pragma unroll
      for (int qg = 0; qg < 4; ++qg)
        pa[qg] = *(const bf16x8*)&Plds[qg * 16 + lo][tk * 32 + hi * 8];
#pragma unroll
      for (int qg = 0; qg < 4; ++qg)
#pragma unroll
        for (int cg = 0; cg < 8; ++cg)
          o[qg][cg] = __builtin_amdgcn_mfma_f32_16x16x32_bf16(pa[qg], vf[tk][cg], o[qg][cg], 0, 0, 0);
    }
  }

  // ---- epilogue
  if (hi == 0) Llds[w * 16 + lo] = lrow;
  __syncthreads();
  f32x4 ll[4];
#pragma unroll
  for (int qg = 0; qg < 4; ++qg) ll[qg] = *(const f32x4*)&Llds[qg * 16 + hi * 4];
  bf16* ob = attnO + ((size_t)h * S_LEN + qb * 64) * 512 + w * 128;
#pragma unroll
  for (int qg = 0; qg < 4; ++qg)
#pragma unroll
    for (int j = 0; j < 4; ++j) {
      const float linv = 1.0f / ll[qg][j];
#pragma unroll
      for (int cg = 0; cg < 8; ++cg)
        ob[(size_t)(qg * 16 + hi * 4 + j) * 512 + cg * 16 + lo] =
            __float2bfloat16(o[qg][cg][j] * linv);
    }
}

// ---------------------------------------------------------------------------
extern "C" void kernel_launch(void* const* d_in, const int* in_sizes, int n_in,
                              void* d_out, int out_size, void* d_ws, size_t ws_size,
                              hipStream_t stream) {
  const float* x       = (const float*)d_in[0];
  const float* wq_a_w  = (const float*)d_in[1];
  const float* wq_a_b  = (const float*)d_in[2];
  const float* q_norm  = (const float*)d_in[3];
  const float* wq_b_w  = (const float*)d_in[4];
  const float* wq_b_b  = (const float*)d_in[5];
  const float* wkv_a_w = (const float*)d_in[6];
  const float* wkv_a_b = (const float*)d_in[7];
  const float* kv_norm = (const float*)d_in[8];
  const float* wkv_b_w = (const float*)d_in[9];
  const float* wo_w    = (const float*)d_in[10];
  const float* wo_bias = (const float*)d_in[11];
  float* out = (float*)d_out;

  char* p = (char*)d_ws;
  auto alloc = [&](size_t bytes) {
    char* r = p;
    p += (bytes + 255) & ~(size_t)255;
    return r;
  };
  bf16*  xb    = (bf16*)alloc(2048ull * 2048 * 2);
  bf16*  wqa   = (bf16*)alloc(1536ull * 2048 * 2);
  bf16*  wqb   = (bf16*)alloc(3072ull * 1536 * 2);
  bf16*  wkva  = (bf16*)alloc(640ull * 2048 * 2);   // padded 576->640
  bf16*  wkvb  = (bf16*)alloc(4096ull * 512 * 2);
  bf16*  wob   = (bf16*)alloc(2048ull * 2048 * 2);
  bf16*  wkvbT = (bf16*)alloc(16ull * 512 * 128 * 2);
  bf16*  qa    = (bf16*)alloc(2048ull * 1536 * 2);
  bf16*  qn    = (bf16*)alloc(2048ull * 1536 * 2);
  bf16*  qv    = (bf16*)alloc(2048ull * 3072 * 2);
  float* kvf   = (float*)alloc(2048ull * 640 * 4);
  bf16*  keff  = (bf16*)alloc(2048ull * 576 * 2);
  bf16*  kvT   = (bf16*)alloc(512ull * 2048 * 2);
  bf16*  Qeff  = (bf16*)alloc(16ull * 2048 * 576 * 2);
  bf16*  attnb = (bf16*)alloc(16ull * 2048 * 512 * 2);
  bf16*  oabs  = (bf16*)alloc(2048ull * 2048 * 2);

  // weight / input converts (fp32 -> bf16, pad wkv_a rows to 640 with zeros)
  cvt_pad4<<<dim3(2048), 256, 0, stream>>>(x, xb, 2048, 2048, 2048);
  cvt_pad4<<<dim3(1024), 256, 0, stream>>>(wq_a_w, wqa, 1536, 2048, 1536);
  cvt_pad4<<<dim3(1024), 256, 0, stream>>>(wq_b_w, wqb, 3072, 1536, 3072);
  cvt_pad4<<<dim3(512), 256, 0, stream>>>(wkv_a_w, wkva, 576, 2048, 640);
  cvt_pad4<<<dim3(512), 256, 0, stream>>>(wkv_b_w, wkvb, 4096, 512, 4096);
  cvt_pad4<<<dim3(1024), 256, 0, stream>>>(wo_w, wob, 2048, 2048, 2048);
  mk_wkvbT<<<dim3(1024), 256, 0, stream>>>(wkvb, wkvbT);

  // q_a = rmsnorm(x @ wq_a^T + b)
  gemm_bt<true, true><<<dim3(12, 16, 1), 256, 0, stream>>>(
      xb, wqa, wq_a_b, qa, 2048, 2048, 1536, 2048, 1536, 0, 0, 0);
  rmsnorm_bf16<<<2048, 256, 0, stream>>>(qa, q_norm, qn, 1536);
  // q = qn @ wq_b^T + b  -> [2048][3072] (bf16)
  gemm_bt<true, true><<<dim3(24, 16, 1), 256, 0, stream>>>(
      qn, wqb, wq_b_b, qv, 1536, 1536, 3072, 1536, 3072, 0, 0, 0);
  // kv_full = x @ wkv_a^T + b -> fp32 [2048][640] (576 valid)
  gemm_bt<true, false><<<dim3(5, 16, 1), 256, 0, stream>>>(
      xb, wkva, wkv_a_b, kvf, 2048, 2048, 640, 2048, 576, 0, 0, 0);
  kv_post<<<2048, 256, 0, stream>>>(kvf, kv_norm, keff);
  transpose_k<<<dim3(16, 64), 256, 0, stream>>>(keff, kvT);
  q_post<<<2048, 256, 0, stream>>>(qv, Qeff);
  // absorbed q_nope: Qeff[h][s][0..512] = q_nope[s][h] @ wkv_bT[h]
  gemm_bt<false, true><<<dim3(4, 16, 16), 256, 0, stream>>>(
      qv, wkvbT, nullptr, Qeff, 3072, 128, 576, 128, 512,
      192ll, 65536ll, 2048ll * 576);
  // attention
  attn_fwd<<<dim3(32, 16), 256, 0, stream>>>(Qeff, keff, kvT, attnb);
  // output absorb: oabs[s][h*128+d] = attn[h][s] @ wkv_b[h][128+d][:]
  gemm_bt<false, true><<<dim3(1, 16, 16), 256, 0, stream>>>(
      attnb, wkvb + 128ull * 512, nullptr, oabs, 512, 512, 2048, 512, 128,
      2048ll * 512, 256ll * 512, 128ll);
  // final: out = oabs @ wo^T + b (fp32 out)
  gemm_bt<true, false><<<dim3(16, 16, 1), 256, 0, stream>>>(
      oabs, wob, wo_bias, out, 2048, 2048, 2048, 2048, 2048, 0, 0, 0);
}